// Round 24
// baseline (118.298 us; speedup 1.0000x reference)
//
#include <hip/hip_runtime.h>
#include <hip/hip_bf16.h>

#define S_LEN 2048
#define NHEAD 16
#define HDIM 64
#define HID 1024
#define BATCH 2
#define TSTR 136   // T-buffer stride (shorts)

typedef __attribute__((ext_vector_type(8))) short s16x8;
typedef __attribute__((ext_vector_type(4))) short s16x4;
typedef __attribute__((ext_vector_type(4))) float f32x4;

__device__ __forceinline__ short f2bf(float f) {
    union { __hip_bfloat16 b; short s; } u;
    u.b = __float2bfloat16(f);
    return u.s;
}
__device__ __forceinline__ float fexp2(float x) {
    return __builtin_amdgcn_exp2f(x);
}
__device__ __forceinline__ f32x4 mfma16(s16x8 a, s16x8 b, f32x4 c) {
    return __builtin_amdgcn_mfma_f32_16x16x32_bf16(a, b, c, 0, 0, 0);
}
__device__ __forceinline__ void gload16(const short* g, short* l) {
    __builtin_amdgcn_global_load_lds(
        (const __attribute__((address_space(1))) void*)g,
        (__attribute__((address_space(3))) void*)l, 16, 0, 0);
}
// pack two f32 -> one u32 of 2 bf16 (round-half-up, inputs finite >=0)
__device__ __forceinline__ unsigned bfpack(float a, float b) {
    unsigned ua = __builtin_bit_cast(unsigned, a) + 0x8000u;
    unsigned ub = __builtin_bit_cast(unsigned, b) + 0x8000u;
    return (ub & 0xFFFF0000u) | (ua >> 16);
}

union P8 { unsigned u[4]; s16x8 v; };
union V8 { s16x4 h[2]; s16x8 v; };

// ---------------------------------------------------------------------------
// Kernel 0: one-shot fp32 -> bf16 conversion of x and all weights.
// ---------------------------------------------------------------------------
__global__ __launch_bounds__(256) void convert_kernel(
    const float* __restrict__ x,  const float* __restrict__ wq,
    const float* __restrict__ wk, const float* __restrict__ wv,
    const float* __restrict__ wo,
    short* __restrict__ xb, short* __restrict__ wcat, short* __restrict__ wob)
{
    const int F4X = 1048576, F4W = 262144;
    const int total = F4X + 4 * F4W;
    for (int i = blockIdx.x * blockDim.x + threadIdx.x; i < total;
         i += gridDim.x * blockDim.x) {
        const float4* s; short* d; int off;
        if (i < F4X)              { s = (const float4*)x;  d = xb;             off = i; }
        else if (i < F4X + F4W)   { s = (const float4*)wq; d = wcat;           off = i - F4X; }
        else if (i < F4X + 2*F4W) { s = (const float4*)wk; d = wcat + 1048576; off = i - (F4X + F4W); }
        else if (i < F4X + 3*F4W) { s = (const float4*)wv; d = wcat + 2097152; off = i - (F4X + 2*F4W); }
        else                      { s = (const float4*)wo; d = wob;            off = i - (F4X + 3*F4W); }
        float4 v = s[off];
        s16x4 o4 = { f2bf(v.x), f2bf(v.y), f2bf(v.z), f2bf(v.w) };
        *(s16x4*)(d + (size_t)off * 4) = o4;
    }
}

// ---------------------------------------------------------------------------
// Kernel 1: fused QKV GEMM, 64x256 block / 4 waves, each wave 64x64 output
// (mi=4, ni=4): A-tile (64 rows) SHARED by all waves, B-slice (64 cols) per
// wave -> 0.5 LDS reads/MFMA (vs 0.75 at 64x128).  768 blocks (3/CU,
// 12 waves/CU), LDS 40KB.  lb<512: Q/K; lb>=512: V operand-swapped
// (dt 0..15 x st 0..15, 256 s-cols).  Two-pass T[64][136] reorder epilogue
// (R18-proven indexing).  Q pre-scaled 0.125, K by log2e.
// ---------------------------------------------------------------------------
__global__ __launch_bounds__(256) void qkv_gemm5(
    const short* __restrict__ xb, const short* __restrict__ wcat,
    short* __restrict__ q_ws, short* __restrict__ k_ws, short* __restrict__ vt_ws)
{
    __shared__ union SM {
        struct { short A[64][64]; short B[256][64]; } s;   // 40 KB
        short T[64][TSTR];                                  // 17.4 KB
    } sm;
    const int t = threadIdx.x;
    const int lane = t & 63, w = t >> 6;           // 4 waves
    const int g = lane >> 4, r15 = lane & 15;
    const int bid = blockIdx.x;
    const int lb = (bid & 7) * 96 + (bid >> 3);    // XCD-chunked, 768%8==0
    const int lrow = lane >> 3;
    const int scol = ((lane & 7) ^ lrow) * 8;      // pre-swizzled source col
    const int rsw = r15 & 7;

    const short* Ag; const short* Bg;
    int sel, m0 = 0, nr0 = 0, dt = 0, st = 0;
    if (lb < 512) {
        const int nt = lb >> 6;                    // 0..7
        const int mt = lb & 63;                    // 0..63
        sel = nt >> 2;                             // 0=q, 1=k
        nr0 = (nt & 3) * 256;
        m0 = mt * 64;
        Ag = xb   + (size_t)m0 * 1024;
        Bg = wcat + (size_t)(sel * 1024 + nr0) * 1024;
    } else {
        const int idx = lb - 512;                  // 0..255
        dt = idx >> 4;                             // 0..15 (64-row d tile)
        st = idx & 15;                             // 0..15 (256-col s tile)
        sel = 2;
        Ag = wcat + (size_t)(2048 + dt * 64) * 1024;
        Bg = xb   + (size_t)st * 256 * 1024;
    }
    const float osc = (sel == 0) ? 0.125f : ((sel == 1) ? 1.44269504f : 1.0f);

    f32x4 acc[4][4] = {};

    for (int k0 = 0; k0 < 1024; k0 += 64) {
        __syncthreads();
        #pragma unroll
        for (int ch = 0; ch < 2; ++ch) {
            const int row = w * 16 + ch * 8;       // A rows 0..63
            gload16(Ag + (size_t)(row + lrow) * 1024 + k0 + scol, &sm.s.A[row][0]);
        }
        #pragma unroll
        for (int ch = 0; ch < 8; ++ch) {
            const int row = w * 64 + ch * 8;       // B rows 0..255
            gload16(Bg + (size_t)(row + lrow) * 1024 + k0 + scol, &sm.s.B[row][0]);
        }
        __syncthreads();
        #pragma unroll
        for (int kk = 0; kk < 2; ++kk) {
            s16x8 af[4], bfr[4];
            #pragma unroll
            for (int mi = 0; mi < 4; ++mi)
                af[mi] = *(const s16x8*)&sm.s.A[mi * 16 + r15][((kk * 4 + g) ^ rsw) * 8];
            #pragma unroll
            for (int ni = 0; ni < 4; ++ni)
                bfr[ni] = *(const s16x8*)&sm.s.B[w * 64 + ni * 16 + r15][((kk * 4 + g) ^ rsw) * 8];
            #pragma unroll
            for (int mi = 0; mi < 4; ++mi)
                #pragma unroll
                for (int ni = 0; ni < 4; ++ni)
                    acc[mi][ni] = mfma16(af[mi], bfr[ni], acc[mi][ni]);
        }
    }

    // ---- epilogue: two 128-col passes through T[64][136] ----
    __syncthreads();
    const int b0 = m0 >> 11;
    const int ms = m0 & 2047;
    #pragma unroll
    for (int ph = 0; ph < 2; ++ph) {
        if ((w >> 1) == ph) {                      // waves {2ph, 2ph+1} fill T
            #pragma unroll
            for (int mi = 0; mi < 4; ++mi)
                #pragma unroll
                for (int ni = 0; ni < 4; ++ni)
                    #pragma unroll
                    for (int reg = 0; reg < 4; ++reg)
                        sm.T[mi * 16 + g * 4 + reg][(w & 1) * 64 + ni * 16 + r15]
                            = f2bf(acc[mi][ni][reg] * osc);
        }
        __syncthreads();
        #pragma unroll
        for (int it = 0; it < 4; ++it) {
            int u = w + it * 4;                    // 0..15
            int half = u & 1;
            int rg = u >> 1;                       // 0..7
            int r = rg * 8 + lrow;                 // 0..63
            int colc = half * 64 + (lane & 7) * 8; // 0..127
            s16x8 v = *(const s16x8*)&sm.T[r][colc];
            if (sel == 2) {
                // d = dt*64 + r (64-aligned): h = dt, dl = r
                int sg = st * 256 + ph * 128 + colc;
                int b = sg >> 11, sl = sg & 2047;
                *(s16x8*)(vt_ws + ((size_t)(b * NHEAD + dt) * HDIM + r) * S_LEN + sl) = v;
            } else {
                int s = ms + r;
                int n = nr0 + ph * 128 + colc;
                int h2 = n >> 6, d = n & 63;
                short* dst = (sel == 0) ? q_ws : k_ws;
                *(s16x8*)(dst + ((size_t)(b0 * NHEAD + h2) * S_LEN + s) * HDIM + d) = v;
            }
        }
        __syncthreads();
    }
}

// ---------------------------------------------------------------------------
// Kernel 2: causal flash attention, R21 proven best (45.6us): supertile
// pairs + KVBLK=128 (two 64-key subtiles per stage -> 17 barriers/pair).
// LDS 64KB, VGPR 132.
// ---------------------------------------------------------------------------
__global__ __launch_bounds__(256) void attn_kernel13(
    const short* __restrict__ q_ws, const short* __restrict__ k_ws,
    const short* __restrict__ vt_ws, short* __restrict__ attn_ws)
{
    __shared__ short Ks[2][128][64];    // [buf][key][d]
    __shared__ short Vts[2][64][128];   // [buf][d][key]
    const int t = threadIdx.x;
    const int lane = t & 63, w = t >> 6;          // w = 0..3
    const int g = lane >> 4, r15 = lane & 15;
    const int bid = blockIdx.x;
    const int lb = (bid & 7) * 32 + (bid >> 3);   // XCD-chunked, 256%8==0
    const int pi = lb & 7;                        // pair index 0..7
    const int bh = lb >> 3;                       // 0..31
    const size_t base = (size_t)bh * S_LEN * HDIM;
    const int swr = (r15 & 7) << 3;
    const int b = bh >> 4, h = bh & 15;

    const int r0 = t >> 3, c0 = (t & 7) * 8;
    const int cx0 = c0 ^ ((r0 & 7) << 3);

    for (int phase = 0; phase < 2; ++phase) {
        const int qt = phase ? (15 - pi) : pi;    // 128-row supertile 0..15
        const int q0 = qt * 128;
        const int nt2 = qt + 1;                   // 128-key iterations
        const int dgt = 2 * qt + (w >> 1);        // wave's diagonal 64-tile
        const int qrel = (w & 1) * 32 + r15;      // + m*16 at use site

        s16x8 qf[2][2];
        #pragma unroll
        for (int m = 0; m < 2; ++m)
            #pragma unroll
            for (int c = 0; c < 2; ++c)
                qf[m][c] = *(const s16x8*)(q_ws + base +
                    (size_t)(q0 + w * 32 + m * 16 + r15) * HDIM + c * 32 + g * 8);
        f32x4 o[2][4] = {};
        float lr[2] = { 0.f, 0.f };

        // prologue: stage key block 0 (128 keys) into buffer 0
        #pragma unroll
        for (int j = 0; j < 4; ++j) {
            int r = r0 + j * 32;                  // K rows 0..127
            *(s16x8*)&Ks[0][r][cx0] =
                *(const s16x8*)(k_ws + base + (size_t)r * HDIM + c0);
        }
        #pragma unroll
        for (int j = 0; j < 2; ++j)
            #pragma unroll
            for (int kk = 0; kk < 2; ++kk) {
                int r = r0 + j * 32;              // V rows (d) 0..63
                *(s16x8*)&Vts[0][r][kk * 64 + cx0] =
                    *(const s16x8*)(vt_ws + base + (size_t)r * S_LEN + kk * 64 + c0);
            }
        __syncthreads();

        for (int it = 0; it < nt2; ++it) {
            const int cur = it & 1;
            const bool pre = (it + 1 < nt2);
            s16x8 ka[4], va[4];
            if (pre) {
                const int kv = (it + 1) * 128;
                #pragma unroll
                for (int j = 0; j < 4; ++j)
                    ka[j] = *(const s16x8*)(k_ws + base +
                        (size_t)(kv + r0 + j * 32) * HDIM + c0);
                #pragma unroll
                for (int j = 0; j < 2; ++j)
                    #pragma unroll
                    for (int kk = 0; kk < 2; ++kk)
                        va[j * 2 + kk] = *(const s16x8*)(vt_ws + base +
                            (size_t)(r0 + j * 32) * S_LEN + kv + kk * 64 + c0);
            }

            #pragma unroll
            for (int s = 0; s < 2; ++s) {
                const int kt = 2 * it + s;
                if (kt <= dgt) {                  // wave-uniform guard
                    const bool dg = (kt == dgt);

                    s16x8 kfa[4][2];
                    #pragma unroll
                    for (int f = 0; f < 4; ++f)
                        #pragma unroll
                        for (int c = 0; c < 2; ++c)
                            kfa[f][c] = *(const s16x8*)&Ks[cur][s * 64 + f * 16 + r15][(c * 32 + g * 8) ^ swr];
                    V8 vfr[4][2];
                    #pragma unroll
                    for (int f2 = 0; f2 < 4; ++f2)
                        #pragma unroll
                        for (int kc = 0; kc < 2; ++kc) {
                            vfr[f2][kc].h[0] = *(const s16x4*)&Vts[cur][f2 * 16 + r15][s * 64 + ((kc * 32 + g * 4) ^ swr)];
                            vfr[f2][kc].h[1] = *(const s16x4*)&Vts[cur][f2 * 16 + r15][s * 64 + ((kc * 32 + 16 + g * 4) ^ swr)];
                        }

                    #pragma unroll
                    for (int m = 0; m < 2; ++m) {
                        f32x4 z[4];
                        __builtin_amdgcn_s_setprio(1);
                        #pragma unroll
                        for (int f = 0; f < 4; ++f) {
                            f32x4 zz = { 0.f, 0.f, 0.f, 0.f };
                            zz = mfma16(kfa[f][0], qf[m][0], zz);
                            zz = mfma16(kfa[f][1], qf[m][1], zz);
                            z[f] = zz;
                        }
                        __builtin_amdgcn_s_setprio(0);

                        if (dg) {
                            const int qr = qrel + m * 16;
                            #pragma unroll
                            for (int f = 0; f < 4; ++f)
                                #pragma unroll
                                for (int reg = 0; reg < 4; ++reg)
                                    if (f * 16 + g * 4 + reg > qr) z[f][reg] = -3e30f;
                        }

                        P8 p8[2];
                        #pragma unroll
                        for (int f = 0; f < 4; ++f) {
                            float e0 = fexp2(z[f][0]);
                            float e1 = fexp2(z[f][1]);
                            float e2 = fexp2(z[f][2]);
                            float e3 = fexp2(z[f][3]);
                            lr[m] += (e0 + e1) + (e2 + e3);
                            p8[f >> 1].u[(f & 1) * 2]     = bfpack(e0, e1);
                            p8[f >> 1].u[(f & 1) * 2 + 1] = bfpack(e2, e3);
                        }

                        __builtin_amdgcn_s_setprio(1);
                        #pragma unroll
                        for (int f2 = 0; f2 < 4; ++f2) {
                            o[m][f2] = mfma16(vfr[f2][0].v, p8[0].v, o[m][f2]);
                            o[m][f2] = mfma16(vfr[f2][1].v, p8[1].v, o[m][f2]);
                        }
                        __builtin_amdgcn_s_setprio(0);
                    }
                }
            }

            if (pre) {
                #pragma unroll
                for (int j = 0; j < 4; ++j)
                    *(s16x8*)&Ks[cur ^ 1][r0 + j * 32][cx0] = ka[j];
                #pragma unroll
                for (int j = 0; j < 2; ++j)
                    #pragma unroll
                    for (int kk = 0; kk < 2; ++kk)
                        *(s16x8*)&Vts[cur ^ 1][r0 + j * 32][kk * 64 + cx0] = va[j * 2 + kk];
            }
            __syncthreads();
        }

        // ---- epilogue: reduce l, normalize, write both m-subtiles ----
        #pragma unroll
        for (int m = 0; m < 2; ++m) {
            float l = lr[m];
            l += __shfl_xor(l, 16);
            l += __shfl_xor(l, 32);
            float inv = 1.f / (l + 1e-8f);
            const int qg = q0 + w * 32 + m * 16 + r15;
            size_t obase = ((size_t)b * S_LEN + qg) * HID + h * HDIM + g * 4;
            #pragma unroll
            for (int f2 = 0; f2 < 4; ++f2) {
                s16x4 ov = { f2bf(o[m][f2][0] * inv), f2bf(o[m][f2][1] * inv),
                             f2bf(o[m][f2][2] * inv), f2bf(o[m][f2][3] * inv) };
                *(s16x4*)(attn_ws + obase + f2 * 16) = ov;
            }
        }
        __syncthreads();   // phase boundary: all reads done before restaging
    }
}

// ---------------------------------------------------------------------------
// Kernel 3: out = attn(bf16) @ wob.T -> fp32.  64x128 tiles, 512 blocks.
// ---------------------------------------------------------------------------
__global__ __launch_bounds__(256) void wo_gemm3(
    const short* __restrict__ attn, const short* __restrict__ wob,
    float* __restrict__ out)
{
    __shared__ short As[64][64];
    __shared__ short Bs[128][64];
    const int t = threadIdx.x;
    const int lane = t & 63, w = t >> 6;
    const int g = lane >> 4, r15 = lane & 15;
    const int bid = blockIdx.x;
    const int cx = bid & 7, ii = bid >> 3;         // ii 0..63
    const int mt = cx * 8 + (ii & 7), nt = ii >> 3;  // 64 x 8
    const int m0 = mt * 64, n0 = nt * 128;
    const int lrow = lane >> 3;
    const int scol = ((lane & 7) ^ lrow) * 8;
    const int rsw = r15 & 7;
    const int wm = w >> 1, wn = w & 1;             // wave tile: 32 x 64

    f32x4 acc[2][4] = {};

    for (int k0 = 0; k0 < 1024; k0 += 64) {
        __syncthreads();
        #pragma unroll
        for (int ch = 0; ch < 2; ++ch) {
            const int row = w * 16 + ch * 8;       // A rows 0..63
            gload16(attn + (size_t)(m0 + row + lrow) * 1024 + k0 + scol, &As[row][0]);
        }
        #pragma unroll
        for (int ch = 0; ch < 4; ++ch) {
            const int row = w * 32 + ch * 8;       // B rows 0..127
            gload16(wob  + (size_t)(n0 + row + lrow) * 1024 + k0 + scol, &Bs[row][0]);
        }
        __syncthreads();
        #pragma unroll
        for (int kk = 0; kk < 2; ++kk) {
            s16x8 af[2], bfr[4];
            #pragma unroll
            for (int mi = 0; mi < 2; ++mi)
                af[mi] = *(const s16x8*)&As[wm * 32 + mi * 16 + r15][((kk * 4 + g) ^ rsw) * 8];
            #pragma unroll
            for (int ni = 0; ni < 4; ++ni)
                bfr[ni] = *(const s16x8*)&Bs[wn * 64 + ni * 16 + r15][((kk * 4 + g) ^ rsw) * 8];
            #pragma unroll
            for (int mi = 0; mi < 2; ++mi)
                #pragma unroll
                for (int ni = 0; ni < 4; ++ni)
                    acc[mi][ni] = mfma16(af[mi], bfr[ni], acc[mi][ni]);
        }
    }

    #pragma unroll
    for (int mi = 0; mi < 2; ++mi)
    #pragma unroll
    for (int ni = 0; ni < 4; ++ni) {
        #pragma unroll
        for (int reg = 0; reg < 4; ++reg) {
            int m = m0 + wm * 32 + mi * 16 + g * 4 + reg;
            int n = n0 + wn * 64 + ni * 16 + r15;
            out[(size_t)m * 1024 + n] = acc[mi][ni][reg];
        }
    }
}

extern "C" void kernel_launch(void* const* d_in, const int* in_sizes, int n_in,
                              void* d_out, int out_size, void* d_ws, size_t ws_size,
                              hipStream_t stream) {
    const float* x  = (const float*)d_in[0];
    const float* wq = (const float*)d_in[1];
    const float* wk = (const float*)d_in[2];
    const float* wv = (const float*)d_in[3];
    const float* wo = (const float*)d_in[4];
    float* out = (float*)d_out;

    const size_t ELEMS = (size_t)BATCH * S_LEN * HID;   // 4,194,304
    short* q_ws    = (short*)d_ws;
    short* k_ws    = q_ws + ELEMS;
    short* vt_ws   = k_ws + ELEMS;
    short* xb      = vt_ws + ELEMS;        // aliased: xb (k0/k1) then attn (k2/k3)
    short* attn_ws = xb;
    short* wcat    = xb + ELEMS;           // 3,145,728
    short* wob     = wcat + 3145728;       // 1,048,576   total ~42MB

    convert_kernel<<<dim3(2048), dim3(256), 0, stream>>>(x, wq, wk, wv, wo, xb, wcat, wob);
    qkv_gemm5<<<dim3(768), dim3(256), 0, stream>>>(xb, wcat, q_ws, k_ws, vt_ws);
    attn_kernel13<<<dim3(256), dim3(256), 0, stream>>>(q_ws, k_ws, vt_ws, attn_ws);
    wo_gemm3<<<dim3(512), dim3(256), 0, stream>>>(attn_ws, wob, out);
}

// Round 25
// 107.021 us; speedup vs baseline: 1.1054x; 1.1054x over previous
//
#include <hip/hip_runtime.h>
#include <hip/hip_bf16.h>

#define S_LEN 2048
#define NHEAD 16
#define HDIM 64
#define HID 1024
#define BATCH 2
#define TSTR 136   // T-buffer stride (shorts)

typedef __attribute__((ext_vector_type(8))) short s16x8;
typedef __attribute__((ext_vector_type(4))) short s16x4;
typedef __attribute__((ext_vector_type(4))) float f32x4;

__device__ __forceinline__ short f2bf(float f) {
    union { __hip_bfloat16 b; short s; } u;
    u.b = __float2bfloat16(f);
    return u.s;
}
__device__ __forceinline__ float fexp2(float x) {
    return __builtin_amdgcn_exp2f(x);
}
__device__ __forceinline__ f32x4 mfma16(s16x8 a, s16x8 b, f32x4 c) {
    return __builtin_amdgcn_mfma_f32_16x16x32_bf16(a, b, c, 0, 0, 0);
}
__device__ __forceinline__ void gload16(const short* g, short* l) {
    __builtin_amdgcn_global_load_lds(
        (const __attribute__((address_space(1))) void*)g,
        (__attribute__((address_space(3))) void*)l, 16, 0, 0);
}
// pack two f32 -> one u32 of 2 bf16 (round-half-up, inputs finite >=0)
__device__ __forceinline__ unsigned bfpack(float a, float b) {
    unsigned ua = __builtin_bit_cast(unsigned, a) + 0x8000u;
    unsigned ub = __builtin_bit_cast(unsigned, b) + 0x8000u;
    return (ub & 0xFFFF0000u) | (ua >> 16);
}

union P8 { unsigned u[4]; s16x8 v; };
union V8 { s16x4 h[2]; s16x8 v; };

// ---------------------------------------------------------------------------
// Kernel 0: one-shot fp32 -> bf16 conversion of x and all weights.
// ---------------------------------------------------------------------------
__global__ __launch_bounds__(256) void convert_kernel(
    const float* __restrict__ x,  const float* __restrict__ wq,
    const float* __restrict__ wk, const float* __restrict__ wv,
    const float* __restrict__ wo,
    short* __restrict__ xb, short* __restrict__ wcat, short* __restrict__ wob)
{
    const int F4X = 1048576, F4W = 262144;
    const int total = F4X + 4 * F4W;
    for (int i = blockIdx.x * blockDim.x + threadIdx.x; i < total;
         i += gridDim.x * blockDim.x) {
        const float4* s; short* d; int off;
        if (i < F4X)              { s = (const float4*)x;  d = xb;             off = i; }
        else if (i < F4X + F4W)   { s = (const float4*)wq; d = wcat;           off = i - F4X; }
        else if (i < F4X + 2*F4W) { s = (const float4*)wk; d = wcat + 1048576; off = i - (F4X + F4W); }
        else if (i < F4X + 3*F4W) { s = (const float4*)wv; d = wcat + 2097152; off = i - (F4X + 2*F4W); }
        else                      { s = (const float4*)wo; d = wob;            off = i - (F4X + 3*F4W); }
        float4 v = s[off];
        s16x4 o4 = { f2bf(v.x), f2bf(v.y), f2bf(v.z), f2bf(v.w) };
        *(s16x4*)(d + (size_t)off * 4) = o4;
    }
}

// ---------------------------------------------------------------------------
// Kernel 1: fused QKV GEMM, 64x128 tiles -> 1536 blocks (6/CU), R20 proven.
// ---------------------------------------------------------------------------
__global__ __launch_bounds__(256) void qkv_gemm4(
    const short* __restrict__ xb, const short* __restrict__ wcat,
    short* __restrict__ q_ws, short* __restrict__ k_ws, short* __restrict__ vt_ws)
{
    __shared__ union SM {
        struct { short A[64][64]; short B[128][64]; } s;   // 24 KB
        short T[64][TSTR];                                  // 17.4 KB
    } sm;
    const int t = threadIdx.x;
    const int lane = t & 63, w = t >> 6;
    const int g = lane >> 4, r15 = lane & 15;
    const int wm = w >> 1, wn = w & 1;             // wave tile: 32 x 64
    const int bid = blockIdx.x;
    const int lb = (bid & 7) * 192 + (bid >> 3);   // XCD-chunked, 1536%8==0
    const int lrow = lane >> 3;
    const int scol = ((lane & 7) ^ lrow) * 8;
    const int rsw = r15 & 7;

    const short* Ag; const short* Bg;
    int sel, m0 = 0, nr0 = 0, dt = 0, st = 0;
    if (lb < 1024) {
        const int nt = lb >> 6;                    // 0..15
        const int mt = lb & 63;                    // 0..63
        sel = nt >> 3;                             // 0=q, 1=k
        nr0 = (nt & 7) * 128;
        m0 = mt * 64;
        Ag = xb   + (size_t)m0 * 1024;
        Bg = wcat + (size_t)(sel * 1024 + nr0) * 1024;
    } else {
        const int idx = lb - 1024;                 // 0..511
        dt = idx >> 5;                             // 0..15 (64-row d tile)
        st = idx & 31;                             // 0..31 (128-col s tile)
        sel = 2;
        Ag = wcat + (size_t)(2048 + dt * 64) * 1024;
        Bg = xb   + (size_t)st * 128 * 1024;
    }
    const float osc = (sel == 0) ? 0.125f : ((sel == 1) ? 1.44269504f : 1.0f);

    f32x4 acc[2][4] = {};

    for (int k0 = 0; k0 < 1024; k0 += 64) {
        __syncthreads();
        #pragma unroll
        for (int ch = 0; ch < 2; ++ch) {
            const int row = w * 16 + ch * 8;       // A rows 0..63
            gload16(Ag + (size_t)(row + lrow) * 1024 + k0 + scol, &sm.s.A[row][0]);
        }
        #pragma unroll
        for (int ch = 0; ch < 4; ++ch) {
            const int row = w * 32 + ch * 8;       // B rows 0..127
            gload16(Bg + (size_t)(row + lrow) * 1024 + k0 + scol, &sm.s.B[row][0]);
        }
        __syncthreads();
        #pragma unroll
        for (int kk = 0; kk < 2; ++kk) {
            s16x8 af[2], bfr[4];
            #pragma unroll
            for (int mi = 0; mi < 2; ++mi)
                af[mi] = *(const s16x8*)&sm.s.A[wm * 32 + mi * 16 + r15][((kk * 4 + g) ^ rsw) * 8];
            #pragma unroll
            for (int ni = 0; ni < 4; ++ni)
                bfr[ni] = *(const s16x8*)&sm.s.B[wn * 64 + ni * 16 + r15][((kk * 4 + g) ^ rsw) * 8];
            #pragma unroll
            for (int mi = 0; mi < 2; ++mi)
                #pragma unroll
                for (int ni = 0; ni < 4; ++ni)
                    acc[mi][ni] = mfma16(af[mi], bfr[ni], acc[mi][ni]);
        }
    }

    __syncthreads();
    #pragma unroll
    for (int mi = 0; mi < 2; ++mi)
    #pragma unroll
    for (int ni = 0; ni < 4; ++ni)
        #pragma unroll
        for (int reg = 0; reg < 4; ++reg)
            sm.T[wm * 32 + mi * 16 + g * 4 + reg][wn * 64 + ni * 16 + r15]
                = f2bf(acc[mi][ni][reg] * osc);
    __syncthreads();

    const int b0 = m0 >> 11;
    const int ms = m0 & 2047;
    #pragma unroll
    for (int it = 0; it < 4; ++it) {
        int u = w + it * 4;
        int half = u & 1;
        int rg = u >> 1;
        int r = rg * 8 + lrow;
        int colc = half * 64 + (lane & 7) * 8;
        s16x8 v = *(const s16x8*)&sm.T[r][colc];
        if (sel == 2) {
            int sg = st * 128 + colc;
            int b = sg >> 11, sl = sg & 2047;
            *(s16x8*)(vt_ws + ((size_t)(b * NHEAD + dt) * HDIM + r) * S_LEN + sl) = v;
        } else {
            int s = ms + r;
            int n = nr0 + colc;
            int h2 = n >> 6, d = n & 63;
            short* dst = (sel == 0) ? q_ws : k_ws;
            *(s16x8*)(dst + ((size_t)(b0 * NHEAD + h2) * S_LEN + s) * HDIM + d) = v;
        }
    }
}

// ---------------------------------------------------------------------------
// Kernel 2: causal flash attention, R21 proven best (45.6us): supertile
// pairs + KVBLK=128 (two 64-key subtiles per stage -> 17 barriers/pair,
// subtile 1's frag reads interleave with subtile 0's compute).  LDS 64KB,
// VGPR 132.
// ---------------------------------------------------------------------------
__global__ __launch_bounds__(256) void attn_kernel13(
    const short* __restrict__ q_ws, const short* __restrict__ k_ws,
    const short* __restrict__ vt_ws, short* __restrict__ attn_ws)
{
    __shared__ short Ks[2][128][64];    // [buf][key][d]
    __shared__ short Vts[2][64][128];   // [buf][d][key]
    const int t = threadIdx.x;
    const int lane = t & 63, w = t >> 6;          // w = 0..3
    const int g = lane >> 4, r15 = lane & 15;
    const int bid = blockIdx.x;
    const int lb = (bid & 7) * 32 + (bid >> 3);   // XCD-chunked, 256%8==0
    const int pi = lb & 7;                        // pair index 0..7
    const int bh = lb >> 3;                       // 0..31
    const size_t base = (size_t)bh * S_LEN * HDIM;
    const int swr = (r15 & 7) << 3;
    const int b = bh >> 4, h = bh & 15;

    const int r0 = t >> 3, c0 = (t & 7) * 8;
    const int cx0 = c0 ^ ((r0 & 7) << 3);

    for (int phase = 0; phase < 2; ++phase) {
        const int qt = phase ? (15 - pi) : pi;    // 128-row supertile 0..15
        const int q0 = qt * 128;
        const int nt2 = qt + 1;                   // 128-key iterations
        const int dgt = 2 * qt + (w >> 1);        // wave's diagonal 64-tile
        const int qrel = (w & 1) * 32 + r15;      // + m*16 at use site

        s16x8 qf[2][2];
        #pragma unroll
        for (int m = 0; m < 2; ++m)
            #pragma unroll
            for (int c = 0; c < 2; ++c)
                qf[m][c] = *(const s16x8*)(q_ws + base +
                    (size_t)(q0 + w * 32 + m * 16 + r15) * HDIM + c * 32 + g * 8);
        f32x4 o[2][4] = {};
        float lr[2] = { 0.f, 0.f };

        // prologue: stage key block 0 (128 keys) into buffer 0
        #pragma unroll
        for (int j = 0; j < 4; ++j) {
            int r = r0 + j * 32;                  // K rows 0..127
            *(s16x8*)&Ks[0][r][cx0] =
                *(const s16x8*)(k_ws + base + (size_t)r * HDIM + c0);
        }
        #pragma unroll
        for (int j = 0; j < 2; ++j)
            #pragma unroll
            for (int kk = 0; kk < 2; ++kk) {
                int r = r0 + j * 32;              // V rows (d) 0..63
                *(s16x8*)&Vts[0][r][kk * 64 + cx0] =
                    *(const s16x8*)(vt_ws + base + (size_t)r * S_LEN + kk * 64 + c0);
            }
        __syncthreads();

        for (int it = 0; it < nt2; ++it) {
            const int cur = it & 1;
            const bool pre = (it + 1 < nt2);
            s16x8 ka[4], va[4];
            if (pre) {
                const int kv = (it + 1) * 128;
                #pragma unroll
                for (int j = 0; j < 4; ++j)
                    ka[j] = *(const s16x8*)(k_ws + base +
                        (size_t)(kv + r0 + j * 32) * HDIM + c0);
                #pragma unroll
                for (int j = 0; j < 2; ++j)
                    #pragma unroll
                    for (int kk = 0; kk < 2; ++kk)
                        va[j * 2 + kk] = *(const s16x8*)(vt_ws + base +
                            (size_t)(r0 + j * 32) * S_LEN + kv + kk * 64 + c0);
            }

            #pragma unroll
            for (int s = 0; s < 2; ++s) {
                const int kt = 2 * it + s;
                if (kt <= dgt) {                  // wave-uniform guard
                    const bool dg = (kt == dgt);

                    s16x8 kfa[4][2];
                    #pragma unroll
                    for (int f = 0; f < 4; ++f)
                        #pragma unroll
                        for (int c = 0; c < 2; ++c)
                            kfa[f][c] = *(const s16x8*)&Ks[cur][s * 64 + f * 16 + r15][(c * 32 + g * 8) ^ swr];
                    V8 vfr[4][2];
                    #pragma unroll
                    for (int f2 = 0; f2 < 4; ++f2)
                        #pragma unroll
                        for (int kc = 0; kc < 2; ++kc) {
                            vfr[f2][kc].h[0] = *(const s16x4*)&Vts[cur][f2 * 16 + r15][s * 64 + ((kc * 32 + g * 4) ^ swr)];
                            vfr[f2][kc].h[1] = *(const s16x4*)&Vts[cur][f2 * 16 + r15][s * 64 + ((kc * 32 + 16 + g * 4) ^ swr)];
                        }

                    #pragma unroll
                    for (int m = 0; m < 2; ++m) {
                        f32x4 z[4];
                        __builtin_amdgcn_s_setprio(1);
                        #pragma unroll
                        for (int f = 0; f < 4; ++f) {
                            f32x4 zz = { 0.f, 0.f, 0.f, 0.f };
                            zz = mfma16(kfa[f][0], qf[m][0], zz);
                            zz = mfma16(kfa[f][1], qf[m][1], zz);
                            z[f] = zz;
                        }
                        __builtin_amdgcn_s_setprio(0);

                        if (dg) {
                            const int qr = qrel + m * 16;
                            #pragma unroll
                            for (int f = 0; f < 4; ++f)
                                #pragma unroll
                                for (int reg = 0; reg < 4; ++reg)
                                    if (f * 16 + g * 4 + reg > qr) z[f][reg] = -3e30f;
                        }

                        P8 p8[2];
                        #pragma unroll
                        for (int f = 0; f < 4; ++f) {
                            float e0 = fexp2(z[f][0]);
                            float e1 = fexp2(z[f][1]);
                            float e2 = fexp2(z[f][2]);
                            float e3 = fexp2(z[f][3]);
                            lr[m] += (e0 + e1) + (e2 + e3);
                            p8[f >> 1].u[(f & 1) * 2]     = bfpack(e0, e1);
                            p8[f >> 1].u[(f & 1) * 2 + 1] = bfpack(e2, e3);
                        }

                        __builtin_amdgcn_s_setprio(1);
                        #pragma unroll
                        for (int f2 = 0; f2 < 4; ++f2) {
                            o[m][f2] = mfma16(vfr[f2][0].v, p8[0].v, o[m][f2]);
                            o[m][f2] = mfma16(vfr[f2][1].v, p8[1].v, o[m][f2]);
                        }
                        __builtin_amdgcn_s_setprio(0);
                    }
                }
            }

            if (pre) {
                #pragma unroll
                for (int j = 0; j < 4; ++j)
                    *(s16x8*)&Ks[cur ^ 1][r0 + j * 32][cx0] = ka[j];
                #pragma unroll
                for (int j = 0; j < 2; ++j)
                    #pragma unroll
                    for (int kk = 0; kk < 2; ++kk)
                        *(s16x8*)&Vts[cur ^ 1][r0 + j * 32][kk * 64 + cx0] = va[j * 2 + kk];
            }
            __syncthreads();
        }

        // ---- epilogue: reduce l, normalize, write both m-subtiles ----
        #pragma unroll
        for (int m = 0; m < 2; ++m) {
            float l = lr[m];
            l += __shfl_xor(l, 16);
            l += __shfl_xor(l, 32);
            float inv = 1.f / (l + 1e-8f);
            const int qg = q0 + w * 32 + m * 16 + r15;
            size_t obase = ((size_t)b * S_LEN + qg) * HID + h * HDIM + g * 4;
            #pragma unroll
            for (int f2 = 0; f2 < 4; ++f2) {
                s16x4 ov = { f2bf(o[m][f2][0] * inv), f2bf(o[m][f2][1] * inv),
                             f2bf(o[m][f2][2] * inv), f2bf(o[m][f2][3] * inv) };
                *(s16x4*)(attn_ws + obase + f2 * 16) = ov;
            }
        }
        __syncthreads();   // phase boundary: all reads done before restaging
    }
}

// ---------------------------------------------------------------------------
// Kernel 3: out = attn(bf16) @ wob.T -> fp32.  64x128 tiles, 512 blocks.
// ---------------------------------------------------------------------------
__global__ __launch_bounds__(256) void wo_gemm3(
    const short* __restrict__ attn, const short* __restrict__ wob,
    float* __restrict__ out)
{
    __shared__ short As[64][64];
    __shared__ short Bs[128][64];
    const int t = threadIdx.x;
    const int lane = t & 63, w = t >> 6;
    const int g = lane >> 4, r15 = lane & 15;
    const int bid = blockIdx.x;
    const int cx = bid & 7, ii = bid >> 3;         // ii 0..63
    const int mt = cx * 8 + (ii & 7), nt = ii >> 3;  // 64 x 8
    const int m0 = mt * 64, n0 = nt * 128;
    const int lrow = lane >> 3;
    const int scol = ((lane & 7) ^ lrow) * 8;
    const int rsw = r15 & 7;
    const int wm = w >> 1, wn = w & 1;             // wave tile: 32 x 64

    f32x4 acc[2][4] = {};

    for (int k0 = 0; k0 < 1024; k0 += 64) {
        __syncthreads();
        #pragma unroll
        for (int ch = 0; ch < 2; ++ch) {
            const int row = w * 16 + ch * 8;       // A rows 0..63
            gload16(attn + (size_t)(m0 + row + lrow) * 1024 + k0 + scol, &As[row][0]);
        }
        #pragma unroll
        for (int ch = 0; ch < 4; ++ch) {
            const int row = w * 32 + ch * 8;       // B rows 0..127
            gload16(wob  + (size_t)(n0 + row + lrow) * 1024 + k0 + scol, &Bs[row][0]);
        }
        __syncthreads();
        #pragma unroll
        for (int kk = 0; kk < 2; ++kk) {
            s16x8 af[2], bfr[4];
            #pragma unroll
            for (int mi = 0; mi < 2; ++mi)
                af[mi] = *(const s16x8*)&As[wm * 32 + mi * 16 + r15][((kk * 4 + g) ^ rsw) * 8];
            #pragma unroll
            for (int ni = 0; ni < 4; ++ni)
                bfr[ni] = *(const s16x8*)&Bs[wn * 64 + ni * 16 + r15][((kk * 4 + g) ^ rsw) * 8];
            #pragma unroll
            for (int mi = 0; mi < 2; ++mi)
                #pragma unroll
                for (int ni = 0; ni < 4; ++ni)
                    acc[mi][ni] = mfma16(af[mi], bfr[ni], acc[mi][ni]);
        }
    }

    #pragma unroll
    for (int mi = 0; mi < 2; ++mi)
    #pragma unroll
    for (int ni = 0; ni < 4; ++ni) {
        #pragma unroll
        for (int reg = 0; reg < 4; ++reg) {
            int m = m0 + wm * 32 + mi * 16 + g * 4 + reg;
            int n = n0 + wn * 64 + ni * 16 + r15;
            out[(size_t)m * 1024 + n] = acc[mi][ni][reg];
        }
    }
}

extern "C" void kernel_launch(void* const* d_in, const int* in_sizes, int n_in,
                              void* d_out, int out_size, void* d_ws, size_t ws_size,
                              hipStream_t stream) {
    const float* x  = (const float*)d_in[0];
    const float* wq = (const float*)d_in[1];
    const float* wk = (const float*)d_in[2];
    const float* wv = (const float*)d_in[3];
    const float* wo = (const float*)d_in[4];
    float* out = (float*)d_out;

    const size_t ELEMS = (size_t)BATCH * S_LEN * HID;   // 4,194,304
    short* q_ws    = (short*)d_ws;
    short* k_ws    = q_ws + ELEMS;
    short* vt_ws   = k_ws + ELEMS;
    short* xb      = vt_ws + ELEMS;        // aliased: xb (k0/k1) then attn (k2/k3)
    short* attn_ws = xb;
    short* wcat    = xb + ELEMS;           // 3,145,728
    short* wob     = wcat + 3145728;       // 1,048,576   total ~42MB

    convert_kernel<<<dim3(2048), dim3(256), 0, stream>>>(x, wq, wk, wv, wo, xb, wcat, wob);
    qkv_gemm4<<<dim3(1536), dim3(256), 0, stream>>>(xb, wcat, q_ws, k_ws, vt_ws);
    attn_kernel13<<<dim3(256), dim3(256), 0, stream>>>(q_ws, k_ws, vt_ws, attn_ws);
    wo_gemm3<<<dim3(512), dim3(256), 0, stream>>>(attn_ws, wob, out);
}